// Round 5
// baseline (1276.237 us; speedup 1.0000x reference)
//
#include <hip/hip_runtime.h>

// 2-layer stacked LSTM: B=256, T=2048, H=64, layer2 hidden=1.
//
// Round-8: DEMAND-FIT register design. Evidence R2-R4: requested VGPR
// budgets are never honored (grants: 64 @5-wave, 184 @1-wave, 132 @2-wave);
// spilled weights re-load from L1/L2 every step (invisible in HBM counters;
// 20-40ms cold dispatch = scratch first-touch). So: lower demand under the
// grant instead of raising the grant.
//
// Structure: 4 waves per batch element (256 blocks x 256 threads).
//  - Layer 1 = R0's proven mapping: wave w, lane l -> gate g=l>>4, unit
//    u=16w+(l&15), column col=g*64+u. ONE W1 column per lane = 64 weights
//    = 64 VGPRs (32 f32x2, v_pk_fma_f32). Total live ~110: fits under every
//    grant observed. All 4 gates of a unit in one wave -> __shfl gather.
//  - amdgpu_waves_per_eu(1,1) now exactly satisfiable (4 waves = 1/SIMD),
//    so the 8-waves/EU default budget (=64, R0/R1's remat cause) is off.
//  - Layer 2 folded into existing waves (R4's proven split + deferral):
//    wave 3 = head (h1(t-1).W2 dot -> staged z4_lds), wave 0 = tail
//    (serial c2/h2, deferred one step). Epilogue verbatim from R4.
//  - ONE __syncthreads per step; h_lds + z stage double-buffered;
//    outputs staged in LDS, bulk-stored at the end.
constexpr int kT = 2048;
constexpr int kB = 256;
constexpr int kH = 64;

typedef __attribute__((ext_vector_type(2))) float f32x2;
typedef __attribute__((ext_vector_type(4))) float f32x4;

__device__ __forceinline__ float fast_sig(float x) {
    return __builtin_amdgcn_rcpf(1.0f + __expf(-x));
}
__device__ __forceinline__ float fast_tanh(float x) {
    float t = __expf(2.0f * x);
    return 1.0f - 2.0f * __builtin_amdgcn_rcpf(t + 1.0f);
}

__global__ __launch_bounds__(256)
__attribute__((amdgpu_waves_per_eu(1, 1)))
void lstm2_kernel(
    const float* __restrict__ x, const float* __restrict__ W1,
    const float* __restrict__ b1, const float* __restrict__ W2,
    const float* __restrict__ b2, float* __restrict__ out)
{
    __shared__ f32x4 x4_lds[kT / 4];      // 8 KB: whole input row
    __shared__ f32x4 out4_lds[kT / 4];    // 8 KB: h2 staging
    __shared__ float h_lds[2][kH];        // 512 B: double-buffered h1
    __shared__ f32x4 z4_lds[2];           // 32 B: double-buffered layer-2 stage

    float* x_lds = (float*)x4_lds;
    float* out_lds = (float*)out4_lds;

    const int tid = threadIdx.x;
    const int b = blockIdx.x;
    const int w = tid >> 6;        // wave 0..3
    const int l = tid & 63;        // lane
    const int g = l >> 4;          // gate: 0=i 1=j 2=f 3=o
    const int s = l & 15;          // unit-within-wave / head slice
    const int u = 16 * w + s;      // layer-1 unit
    const int col = g * 64 + u;    // W1 column (gate-major)

    const f32x4* xg4 = (const f32x4*)(x + (size_t)b * kT);
    f32x4* outg4 = (f32x4*)(out + (size_t)b * kT);

    for (int i = tid; i < kT / 4; i += 256) x4_lds[i] = xg4[i];
    if (tid < kH) { h_lds[0][tid] = 0.0f; h_lds[1][tid] = 0.0f; }

    // ---- layer-1 weights: ONE column (64 h-weights) per lane ----
    // wh[j] pairs (h[2j], h[2j+1]); W1 row r+1 multiplies h[r].
    const float w0  = W1[col];
    const float b1g = b1[col];
    f32x2 wh[32];
    #pragma unroll
    for (int j = 0; j < 32; ++j) {
        wh[j].x = W1[(2 * j + 1) * 256 + col];
        wh[j].y = W1[(2 * j + 2) * 256 + col];
    }
    // ---- layer-2 weights (all lanes; wave3 uses in-loop, wave0 epilogue) --
    const float w2p0 = W2[(s +  0) * 4 + g];
    const float w2p1 = W2[(s + 16) * 4 + g];
    const float w2p2 = W2[(s + 32) * 4 + g];
    const float w2p3 = W2[(s + 48) * 4 + g];
    const float b2g  = b2[g];
    f32x4 w2t = ((const f32x4*)W2)[kH];   // W2[64][0..3]: h2 recurrent row

    // ---- PIN loop invariants (blocks rematerialization of the loads) ----
    #pragma unroll
    for (int j = 0; j < 32; ++j) asm volatile("" : "+v"(wh[j]));
    asm volatile("" : "+v"(w2t));

    float c1 = 0.0f, c2 = 0.0f, h2 = 0.0f;

    __syncthreads();

    #pragma unroll 1
    for (int t = 0; t < kT; ++t) {
        const int cur = t & 1, nxt = cur ^ 1;
        const float xt = x_lds[t];

        if (w == 0) {
            // ---- layer-2 tail: c2/h2 recurrence, output step t-2 ----
            if (t >= 2) {
                const f32x4 z4 = z4_lds[nxt];     // staged at t-1 (bias incl.)
                const float zi = z4.x + h2 * w2t.x;
                const float zj = z4.y + h2 * w2t.y;
                const float zf = z4.z + h2 * w2t.z;
                const float zo = z4.w + h2 * w2t.w;
                c2 = fast_sig(zf + 1.0f) * c2 + fast_sig(zi) * fast_tanh(zj);
                h2 = fast_sig(zo) * fast_tanh(c2);
                if (l == 0) out_lds[t - 2] = h2;
            }
        } else if (w == 3) {
            // ---- layer-2 head: h1(t-1) . W2 cols, staged to z4_lds[cur] ----
            if (t >= 1) {
                const float* hb = h_lds[cur];
                float pr = hb[s] * w2p0;
                pr = fmaf(hb[s + 16], w2p1, pr);
                pr = fmaf(hb[s + 32], w2p2, pr);
                pr = fmaf(hb[s + 48], w2p3, pr);
                pr += __shfl_xor(pr, 1);
                pr += __shfl_xor(pr, 2);
                pr += __shfl_xor(pr, 4);
                pr += __shfl_xor(pr, 8);
                if (s == 0) ((float*)&z4_lds[cur])[g] = pr + b2g;
            }
        }

        // ---- layer-1 (ALL waves): z = b + x*w0 + h(t-1) . wh ----
        const f32x4* hb4 = (const f32x4*)h_lds[cur];   // broadcast b128 reads
        f32x2 a0 = {fmaf(xt, w0, b1g), 0.0f};
        f32x2 a1 = {0.0f, 0.0f}, a2 = {0.0f, 0.0f}, a3 = {0.0f, 0.0f};
        #pragma unroll
        for (int k = 0; k < 16; k += 2) {
            const f32x4 hA = hb4[k];
            const f32x4 hB = hb4[k + 1];
            a0 += hA.xy * wh[2 * k];
            a1 += hA.zw * wh[2 * k + 1];
            a2 += hB.xy * wh[2 * k + 2];
            a3 += hB.zw * wh[2 * k + 3];
        }
        const f32x2 bb = (a0 + a1) + (a2 + a3);
        const float z = bb.x + bb.y;
        // g==1 -> tanh(z) = 2*sig(2z)-1; g==2 -> sig(z+1); else sig(z)
        const float zz = (g == 1) ? 2.0f * z : ((g == 2) ? z + 1.0f : z);
        const float sg = fast_sig(zz);
        const float a = (g == 1) ? fmaf(2.0f, sg, -1.0f) : sg;
        // gather the 4 gates of unit u (all within this wave)
        const float ai = __shfl(a, s);
        const float aj = __shfl(a, s + 16);
        const float af = __shfl(a, s + 32);
        const float ao = __shfl(a, s + 48);
        c1 = fmaf(af, c1, ai * aj);               // redundant in 4 lane-groups
        const float h1n = ao * fast_tanh(c1);
        if (g == 0) h_lds[nxt][u] = h1n;          // 16 writes per wave

        __syncthreads();
    }

    // ---- epilogue (wave 0): outputs T-2 and T-1 (verbatim R4 scheme) ----
    if (w == 0) {
        {   // out[T-2]: z staged by wave3 at t = T-1 into slot (T-1)&1 = 1
            const f32x4 z4 = z4_lds[1];
            const float zi = z4.x + h2 * w2t.x;
            const float zj = z4.y + h2 * w2t.y;
            const float zf = z4.z + h2 * w2t.z;
            const float zo = z4.w + h2 * w2t.w;
            c2 = fast_sig(zf + 1.0f) * c2 + fast_sig(zi) * fast_tanh(zj);
            h2 = fast_sig(zo) * fast_tanh(c2);
            if (l == 0) out_lds[kT - 2] = h2;
        }
        {   // out[T-1]: head computed here from h1(T-1) = h_lds[0]
            const float* hb = h_lds[0];
            float pr = hb[s] * w2p0;
            pr = fmaf(hb[s + 16], w2p1, pr);
            pr = fmaf(hb[s + 32], w2p2, pr);
            pr = fmaf(hb[s + 48], w2p3, pr);
            pr += __shfl_xor(pr, 1);
            pr += __shfl_xor(pr, 2);
            pr += __shfl_xor(pr, 4);
            pr += __shfl_xor(pr, 8);
            const float prb = pr + b2g;
            const float zi = __shfl(prb,  0) + h2 * w2t.x;
            const float zj = __shfl(prb, 16) + h2 * w2t.y;
            const float zf = __shfl(prb, 32) + h2 * w2t.z;
            const float zo = __shfl(prb, 48) + h2 * w2t.w;
            c2 = fast_sig(zf + 1.0f) * c2 + fast_sig(zi) * fast_tanh(zj);
            h2 = fast_sig(zo) * fast_tanh(c2);
            if (l == 0) out_lds[kT - 1] = h2;
        }
    }

    // ---- bulk coalesced store of the whole output row ----
    __syncthreads();
    for (int i = tid; i < kT / 4; i += 256) outg4[i] = out4_lds[i];
}

extern "C" void kernel_launch(void* const* d_in, const int* in_sizes, int n_in,
                              void* d_out, int out_size, void* d_ws, size_t ws_size,
                              hipStream_t stream) {
    const float* x  = (const float*)d_in[0];
    const float* W1 = (const float*)d_in[1];
    const float* b1 = (const float*)d_in[2];
    const float* W2 = (const float*)d_in[3];
    const float* b2 = (const float*)d_in[4];
    float* out = (float*)d_out;
    lstm2_kernel<<<kB, 256, 0, stream>>>(x, W1, b1, W2, b2, out);
}

// Round 6
// 1219.344 us; speedup vs baseline: 1.0467x; 1.0467x over previous
//
#include <hip/hip_runtime.h>

// 2-layer stacked LSTM: B=256, T=2048, H=64, layer2 hidden=1.
//
// Round-9: cut the serial barrier-to-barrier chain.
// Evidence R5: weights resident (VGPR 132, no scratch) yet SLOWER than R0
// (weights re-fetched every step) -> operand supply is irrelevant; the
// per-step serial chain is everything. R5's folded layer-2 head (LDS read +
// 4 ds_bpermute, ~250cy) sat serially in the chain; the gate gather's 4
// ds_bpermute (~140cy LDS-pipe latency) likewise.
//
// Structure: 4 waves (256 thr) per batch element, 256 blocks.
//  - QUAD GATE MAPPING: lane l -> unit u = 16w + (l>>2), gate g = l&3.
//    All 4 gates of a unit in one quad -> gather = 3 quad_perm DPP movs
//    (~12cy VALU) instead of 4 ds_bpermute (~140cy LDS). Only g==0 lanes
//    carry the true c1/h1 chain (other lanes compute bounded garbage that
//    is never written: sig/tanh outputs are bounded, no NaN/Inf).
//  - LAYER 2 OUT OF THE LOOP: in-loop we only compute the 4-float input
//    projection z~(t) = W2^T h1(t) + b2 (wave w computes gate w: one
//    lane-distinct b32 read + 1 FMA + 6-op DPP full-wave reduce, off the
//    critical path) into a 32KB LDS buffer. The serial c2/h2 recurrence
//    runs POST-LOOP as a scan on wave 0 (~65cy/step ~= 55us, reads
//    prefetchable). Main loop: all 4 waves symmetric, ONE barrier/step.
constexpr int kT = 2048;
constexpr int kB = 256;
constexpr int kH = 64;

typedef __attribute__((ext_vector_type(2))) float f32x2;
typedef __attribute__((ext_vector_type(4))) float f32x4;

__device__ __forceinline__ float fast_sig(float x) {
    return __builtin_amdgcn_rcpf(1.0f + __expf(-x));
}
__device__ __forceinline__ float fast_tanh(float x) {
    float t = __expf(2.0f * x);
    return 1.0f - 2.0f * __builtin_amdgcn_rcpf(t + 1.0f);
}
// DPP permute-mov of v (bound_ctrl=1: invalid lanes read 0).
template <int CTRL>
__device__ __forceinline__ float dpp_mov(float v) {
    return __int_as_float(__builtin_amdgcn_update_dpp(
        0, __float_as_int(v), CTRL, 0xF, 0xF, true));
}
// acc += dpp_perm(acc): one step of a full-wave DPP reduction.
template <int CTRL>
__device__ __forceinline__ float dpp_add(float acc) {
    int t = __builtin_amdgcn_update_dpp(
        0, __float_as_int(acc), CTRL, 0xF, 0xF, true);
    return acc + __int_as_float(t);
}
// Full 64-lane sum; result valid in lane 63 (classic GCN row_shr/bcast tree).
__device__ __forceinline__ float wave_sum_to63(float v) {
    v = dpp_add<0x111>(v);  // row_shr:1
    v = dpp_add<0x112>(v);  // row_shr:2
    v = dpp_add<0x114>(v);  // row_shr:4
    v = dpp_add<0x118>(v);  // row_shr:8  -> lane15-of-row = row sum
    v = dpp_add<0x142>(v);  // row_bcast15 -> lane31 = sum(0..31), lane63 = sum(32..63)
    v = dpp_add<0x143>(v);  // row_bcast31 -> lane63 = total
    return v;
}

__global__ __launch_bounds__(256)
__attribute__((amdgpu_waves_per_eu(1, 1)))
void lstm2_kernel(
    const float* __restrict__ x, const float* __restrict__ W1,
    const float* __restrict__ b1, const float* __restrict__ W2,
    const float* __restrict__ b2, float* __restrict__ out)
{
    __shared__ f32x4 x4_lds[kT / 4];      // 8 KB: whole input row
    __shared__ f32x4 out4_lds[kT / 4];    // 8 KB: h2 staging
    __shared__ f32x4 z4_lds[kT];          // 32 KB: z~(t) for the post-loop scan
    __shared__ float h_lds[2][kH];        // 512 B: double-buffered h1

    float* x_lds = (float*)x4_lds;
    float* out_lds = (float*)out4_lds;
    float* z_lds = (float*)z4_lds;

    const int tid = threadIdx.x;
    const int b = blockIdx.x;
    const int w = tid >> 6;        // wave 0..3 (also: layer-2 gate this wave reduces)
    const int l = tid & 63;        // lane
    const int g = l & 3;           // layer-1 gate: 0=i 1=j 2=f 3=o (quad mapping)
    const int u = 16 * w + (l >> 2);  // layer-1 unit
    const int col = g * 64 + u;    // W1 column (gate-major: i,j,f,o blocks)

    const f32x4* xg4 = (const f32x4*)(x + (size_t)b * kT);
    f32x4* outg4 = (f32x4*)(out + (size_t)b * kT);

    for (int i = tid; i < kT / 4; i += 256) x4_lds[i] = xg4[i];
    if (tid < kH) { h_lds[0][tid] = 0.0f; h_lds[1][tid] = 0.0f; }

    // ---- layer-1 weights: ONE column (64 h-weights) per lane ----
    // wh[j] pairs (h[2j], h[2j+1]); W1 row r+1 multiplies h[r].
    const float w0  = W1[col];
    const float b1g = b1[col];
    f32x2 wh[32];
    #pragma unroll
    for (int j = 0; j < 32; ++j) {
        wh[j].x = W1[(2 * j + 1) * 256 + col];
        wh[j].y = W1[(2 * j + 2) * 256 + col];
    }
    // ---- layer-2 projection weights: wave w reduces gate w ----
    const float w2c = W2[l * 4 + w];   // W2[h-row l][gate w]
    const float b2w = b2[w];

    // ---- PIN loop invariants (blocks rematerialization of the loads) ----
    #pragma unroll
    for (int j = 0; j < 32; ++j) asm volatile("" : "+v"(wh[j]));

    float c1 = 0.0f;

    __syncthreads();

    #pragma unroll 1
    for (int t = 0; t < kT; ++t) {
        const int cur = t & 1, nxt = cur ^ 1;

        // ---- layer-2 projection for step t-1 (off critical path):
        //      z~[t-1][w] = sum_l h1(t-1)[l] * W2[l][w] + b2[w]  ----
        if (t >= 1) {
            float pr = h_lds[cur][l] * w2c;    // lane-distinct b32 read
            pr = wave_sum_to63(pr);            // 6 DPP adds, VALU pipe
            const float zt = __int_as_float(
                __builtin_amdgcn_readlane(__float_as_int(pr), 63)) + b2w;
            if (l == 0) z_lds[(t - 1) * 4 + w] = zt;
        }

        // ---- layer-1: z = b + x*w0 + h(t-1) . wh  (broadcast b128 reads) --
        const float xt = x_lds[t];
        const f32x4* hb4 = (const f32x4*)h_lds[cur];
        f32x2 a0 = {fmaf(xt, w0, b1g), 0.0f};
        f32x2 a1 = {0.0f, 0.0f}, a2 = {0.0f, 0.0f}, a3 = {0.0f, 0.0f};
        #pragma unroll
        for (int k = 0; k < 16; k += 2) {
            const f32x4 hA = hb4[k];
            const f32x4 hB = hb4[k + 1];
            a0 += hA.xy * wh[2 * k];
            a1 += hA.zw * wh[2 * k + 1];
            a2 += hB.xy * wh[2 * k + 2];
            a3 += hB.zw * wh[2 * k + 3];
        }
        const f32x2 bb = (a0 + a1) + (a2 + a3);
        const float z = bb.x + bb.y;
        // g==1 -> tanh(z) = 2*sig(2z)-1; g==2 -> sig(z+1); else sig(z)
        const float zz = (g == 1) ? 2.0f * z : ((g == 2) ? z + 1.0f : z);
        const float sg = fast_sig(zz);
        const float a = (g == 1) ? fmaf(2.0f, sg, -1.0f) : sg;
        // gather within the QUAD: for g==0 lanes a=i, xor1->j, xor2->f, xor3->o
        const float aj = dpp_mov<0xB1>(a);   // quad_perm [1,0,3,2]
        const float af = dpp_mov<0x4E>(a);   // quad_perm [2,3,0,1]
        const float ao = dpp_mov<0x1B>(a);   // quad_perm [3,2,1,0]
        c1 = fmaf(af, c1, a * aj);           // true chain only in g==0 lanes
        const float h1n = ao * fast_tanh(c1);
        if (g == 0) h_lds[nxt][u] = h1n;     // 16 b32 writes per wave

        __syncthreads();
    }

    // ---- final projection z~[kT-1] from h1(kT-1) (in h_lds[0]) ----
    {
        float pr = h_lds[0][l] * w2c;
        pr = wave_sum_to63(pr);
        const float zt = __int_as_float(
            __builtin_amdgcn_readlane(__float_as_int(pr), 63)) + b2w;
        if (l == 0) z_lds[(kT - 1) * 4 + w] = zt;
    }
    __syncthreads();

    // ---- layer-2 scan (wave 0; all lanes redundant, lane 0 writes) ----
    if (w == 0) {
        const f32x4 w2t = ((const f32x4*)W2)[kH];  // h2 recurrent row
        float c2 = 0.0f, h2 = 0.0f;
        #pragma unroll 2
        for (int t2 = 0; t2 < kT; ++t2) {
            const f32x4 z4 = z4_lds[t2];           // broadcast, prefetchable
            const float zi = z4.x + h2 * w2t.x;
            const float zj = z4.y + h2 * w2t.y;
            const float zf = z4.z + h2 * w2t.z;
            const float zo = z4.w + h2 * w2t.w;
            c2 = fast_sig(zf + 1.0f) * c2 + fast_sig(zi) * fast_tanh(zj);
            h2 = fast_sig(zo) * fast_tanh(c2);
            if (l == 0) out_lds[t2] = h2;
        }
    }
    __syncthreads();

    // ---- bulk coalesced store of the whole output row ----
    for (int i = tid; i < kT / 4; i += 256) outg4[i] = out4_lds[i];
}

extern "C" void kernel_launch(void* const* d_in, const int* in_sizes, int n_in,
                              void* d_out, int out_size, void* d_ws, size_t ws_size,
                              hipStream_t stream) {
    const float* x  = (const float*)d_in[0];
    const float* W1 = (const float*)d_in[1];
    const float* b1 = (const float*)d_in[2];
    const float* W2 = (const float*)d_in[3];
    const float* b2 = (const float*)d_in[4];
    float* out = (float*)d_out;
    lstm2_kernel<<<kB, 256, 0, stream>>>(x, W1, b1, W2, b2, out);
}